// Round 1
// baseline (846.303 us; speedup 1.0000x reference)
//
#include <hip/hip_runtime.h>

#define T_LEN 32768
#define TT 64   // t-tile per block

// Fused WaveNet block: dilated causal conv (K=3, DIL=8) + cond 1x1 + gate + out 1x1.
// Block = 256 threads (4 waves), one (b, 64-wide t tile) per block.
// lanes <-> t; waves split the 64 gate-row-pairs (r, r+64), 16 pairs/wave.
__global__ __launch_bounds__(256, 2) void wavenet_fused(
    const float* __restrict__ x, const float* __restrict__ cond,
    const float* __restrict__ wconv, const float* __restrict__ bconv,
    const float* __restrict__ wout, const float* __restrict__ bout,
    const float* __restrict__ wcond,
    float* __restrict__ out, float* __restrict__ skip)
{
    __shared__ float xs[64][80];   // x[b, c, t0-16 .. t0+64)
    __shared__ float cs[80][64];   // cond[b, cc, t0 .. t0+64)
    __shared__ float zs[64][64];   // gated activations

    const int bid = blockIdx.x;
    const int b  = bid >> 9;          // 512 tiles per batch
    const int t0 = (bid & 511) * TT;
    const int tid = threadIdx.x;

    // ---- stage x tile (with 16-col causal halo, zero-filled at t<0) ----
    for (int e = tid; e < 64 * 80; e += 256) {
        int c = e / 80, j = e - c * 80;
        int gt = t0 - 16 + j;
        xs[c][j] = (gt >= 0) ? x[(size_t)(b * 64 + c) * T_LEN + gt] : 0.f;
    }
    // ---- stage cond tile ----
    for (int e = tid; e < 80 * 64; e += 256) {
        int cc = e >> 6, j = e & 63;
        cs[cc][j] = cond[(size_t)(b * 80 + cc) * T_LEN + t0 + j];
    }
    __syncthreads();

    const int wv   = __builtin_amdgcn_readfirstlane(tid >> 6);  // force wave-uniform
    const int lane = tid & 63;                                   // lane <-> t offset

    // ---- phase 1: y = conv + cond + bias; gate; 4 row-pairs per pass ----
    for (int rg = 0; rg < 4; ++rg) {
        const int r0 = wv * 16 + rg * 4;
        float acc[8];
        #pragma unroll
        for (int i = 0; i < 4; ++i) {
            acc[i]     = bconv[r0 + i];
            acc[4 + i] = bconv[r0 + i + 64];
        }
        // dilated conv taps: x[t-16], x[t-8], x[t]  (cols lane, lane+8, lane+16)
        for (int c = 0; c < 64; ++c) {
            float xv0 = xs[c][lane];
            float xv1 = xs[c][lane + 8];
            float xv2 = xs[c][lane + 16];
            #pragma unroll
            for (int i = 0; i < 4; ++i) {
                const float* wp = wconv + (size_t)(r0 + i) * 192 + c * 3;
                acc[i]     += wp[0] * xv0 + wp[1] * xv1 + wp[2] * xv2;
                const float* wq = wconv + (size_t)(r0 + i + 64) * 192 + c * 3;
                acc[4 + i] += wq[0] * xv0 + wq[1] * xv1 + wq[2] * xv2;
            }
        }
        // conditioning 1x1
        for (int cc = 0; cc < 80; ++cc) {
            float cv = cs[cc][lane];
            #pragma unroll
            for (int i = 0; i < 4; ++i) {
                acc[i]     += wcond[(size_t)(r0 + i) * 80 + cc] * cv;
                acc[4 + i] += wcond[(size_t)(r0 + i + 64) * 80 + cc] * cv;
            }
        }
        // gate: z = tanh(a) * sigmoid(g)   (NaN-safe forms for |a|,|g| large)
        #pragma unroll
        for (int i = 0; i < 4; ++i) {
            float a = acc[i], g = acc[4 + i];
            float e2 = __expf(2.f * a);
            float th = 1.f - 2.f * __builtin_amdgcn_rcpf(e2 + 1.f);
            float sg = __builtin_amdgcn_rcpf(1.f + __expf(-g));
            float z = th * sg;
            zs[r0 + i][lane] = z;
            skip[(size_t)(b * 64 + r0 + i) * T_LEN + t0 + lane] = z;
        }
    }
    __syncthreads();

    // ---- phase 2: out = Wout @ z + bias ----
    for (int og = 0; og < 4; ++og) {
        const int o0 = wv * 16 + og * 4;
        float acc[4];
        #pragma unroll
        for (int i = 0; i < 4; ++i) acc[i] = bout[o0 + i];
        for (int r = 0; r < 64; ++r) {
            float zv = zs[r][lane];
            #pragma unroll
            for (int i = 0; i < 4; ++i)
                acc[i] += wout[(size_t)(o0 + i) * 64 + r] * zv;
        }
        #pragma unroll
        for (int i = 0; i < 4; ++i)
            out[(size_t)(b * 64 + o0 + i) * T_LEN + t0 + lane] = acc[i];
    }
}

extern "C" void kernel_launch(void* const* d_in, const int* in_sizes, int n_in,
                              void* d_out, int out_size, void* d_ws, size_t ws_size,
                              hipStream_t stream) {
    const float* x     = (const float*)d_in[0];
    const float* cond  = (const float*)d_in[1];
    const float* wconv = (const float*)d_in[2];
    const float* bconv = (const float*)d_in[3];
    const float* wout  = (const float*)d_in[4];
    const float* bout  = (const float*)d_in[5];
    const float* wcond = (const float*)d_in[6];

    float* out  = (float*)d_out;
    float* skip = out + (size_t)8 * 64 * T_LEN;   // outputs concatenated in return order

    dim3 grid(8 * (T_LEN / TT));   // 4096 blocks: (b, t-tile)
    wavenet_fused<<<grid, 256, 0, stream>>>(x, cond, wconv, bconv, wout, bout, wcond,
                                            out, skip);
}

// Round 2
// 122.272 us; speedup vs baseline: 6.9215x; 6.9215x over previous
//
#include <hip/hip_runtime.h>

#define T_LEN 32768
#define TT 128

typedef unsigned short ushort;
typedef unsigned int uint;
typedef __attribute__((ext_vector_type(8))) short short8;   // 8 bf16 (4 VGPRs)
typedef __attribute__((ext_vector_type(4))) float f32x4;

// Fragment-packed bf16 weights (written by pack_weights every launch — deterministic).
__device__ __align__(16) ushort g_packA1[9 * 8 * 64 * 8];   // conv(3 taps)+cond, 9 k-steps x 8 M-frags
__device__ __align__(16) ushort g_packA2[2 * 4 * 64 * 8];   // wout, 2 k-steps x 4 M-frags

static __device__ __forceinline__ ushort f2bf(float f) {    // RNE f32->bf16
    uint u = __float_as_uint(f);
    u += 0x7fffu + ((u >> 16) & 1u);
    return (ushort)(u >> 16);
}

// A-fragment layout for mfma_f32_16x16x32_bf16: lane l holds A[16m + (l&15)][32s + (l>>4)*8 + j]
__global__ void pack_weights(const float* __restrict__ wconv,
                             const float* __restrict__ wcond,
                             const float* __restrict__ wout) {
    int idx = blockIdx.x * 256 + threadIdx.x;
    if (idx < 9 * 8 * 64 * 8) {
        int j = idx & 7, l = (idx >> 3) & 63, m = (idx >> 9) & 7, s = idx >> 12;
        int row = m * 16 + (l & 15);
        int k = s * 32 + ((l >> 4) << 3) + j;          // 0..287
        float v;
        if (k < 192) v = wconv[row * 192 + (k & 63) * 3 + (k >> 6)];   // tap = k/64, c = k%64
        else { int cc = k - 192; v = (cc < 80) ? wcond[row * 80 + cc] : 0.f; }
        g_packA1[idx] = f2bf(v);
    } else {
        int e = idx - 9 * 8 * 64 * 8;                   // 4096 elems
        int j = e & 7, l = (e >> 3) & 63, m = (e >> 9) & 3, s = e >> 11;
        int row = m * 16 + (l & 15);
        int k = s * 32 + ((l >> 4) << 3) + j;           // 0..63
        g_packA2[e] = f2bf(wout[row * 64 + k]);
    }
}

// 4 waves as 2x2 (mw x nw). Wave computes rows {32mw..+32} U {64+32mw..+32} x cols {64nw..+64}.
// Gate pairs (r, r+64) live in the same lane/reg -> register-only gate.
__global__ __launch_bounds__(256) void wavenet_mfma(
    const float* __restrict__ x, const float* __restrict__ cond,
    const float* __restrict__ bconv, const float* __restrict__ bout,
    float* __restrict__ out, float* __restrict__ skip)
{
    // xs: [144 t][64 c] bf16, 128B rows, chunk-XOR swizzle; zs overlays after phase A.
    // cs: [128 t][128 cc] bf16 (cc padded to 96 with zeros), 256B rows, same swizzle.
    __shared__ __align__(16) char lds[18432 + 32768];
    char* xs = lds;
    char* cs = lds + 18432;

    const int b   = blockIdx.x >> 8;
    const int t0  = (blockIdx.x & 255) * TT;
    const int tid = threadIdx.x;

    // ---- stage x tile (16-col causal halo, zero-filled at t<0) ----
    for (int e = tid; e < 64 * 144; e += 256) {
        int c = e / 144, tl = e - c * 144;
        int gt = t0 - 16 + tl;
        float v = (gt >= 0) ? x[(size_t)(b * 64 + c) * T_LEN + gt] : 0.f;
        *(ushort*)(xs + tl * 128 + ((c * 2) ^ ((tl & 7) << 4))) = f2bf(v);
    }
    // ---- stage cond tile + zero pad cc 80..96 ----
    for (int e = tid; e < 80 * 128; e += 256) {
        int cc = e >> 7, tl = e & 127;
        float v = cond[(size_t)(b * 80 + cc) * T_LEN + t0 + tl];
        *(ushort*)(cs + tl * 256 + ((cc * 2) ^ ((tl & 7) << 4))) = f2bf(v);
    }
    for (int e = tid; e < 16 * 128; e += 256) {
        int cc = 80 + (e >> 7), tl = e & 127;
        *(ushort*)(cs + tl * 256 + ((cc * 2) ^ ((tl & 7) << 4))) = 0;
    }
    __syncthreads();

    const int lane = tid & 63;
    const int wv = tid >> 6;
    const int mw = wv & 1, nw = wv >> 1;
    const int l4 = lane >> 4, l15 = lane & 15;

    // ---- phase A: y = Wconv(*)x + Wcond*c + bconv ----
    f32x4 accA[2][4], accG[2][4];
    #pragma unroll
    for (int i = 0; i < 2; ++i) {
        int rbase = mw * 32 + i * 16 + l4 * 4;
        #pragma unroll
        for (int j = 0; j < 4; ++j) {
            float ba = bconv[rbase + j];
            float bg = bconv[64 + rbase + j];
            #pragma unroll
            for (int ni = 0; ni < 4; ++ni) { accA[i][ni][j] = ba; accG[i][ni][j] = bg; }
        }
    }

    const short8* pA1 = (const short8*)g_packA1;
    #pragma unroll
    for (int s = 0; s < 9; ++s) {
        short8 B[4];
        #pragma unroll
        for (int ni = 0; ni < 4; ++ni) {
            int col = nw * 64 + ni * 16 + l15;
            if (s < 6) {   // conv tap s>>1, c-half s&1: B[k=c][n=t], tap shifts t by 8*tap
                int tl = col + (s >> 1) * 8;
                int bc = (s & 1) * 64 + l4 * 16;
                B[ni] = *(const short8*)(xs + tl * 128 + (bc ^ ((tl & 7) << 4)));
            } else {       // cond k-step
                int bc = (s - 6) * 64 + l4 * 16;
                B[ni] = *(const short8*)(cs + col * 256 + (bc ^ ((col & 7) << 4)));
            }
        }
        #pragma unroll
        for (int i = 0; i < 2; ++i) {
            short8 Aa = pA1[(s * 8 + mw * 2 + i) * 64 + lane];
            short8 Ag = pA1[(s * 8 + 4 + mw * 2 + i) * 64 + lane];
            #pragma unroll
            for (int ni = 0; ni < 4; ++ni) {
                accA[i][ni] = __builtin_amdgcn_mfma_f32_16x16x32_bf16(Aa, B[ni], accA[i][ni], 0, 0, 0);
                accG[i][ni] = __builtin_amdgcn_mfma_f32_16x16x32_bf16(Ag, B[ni], accG[i][ni], 0, 0, 0);
            }
        }
    }
    __syncthreads();   // all xs reads done -> safe to overlay zs

    // ---- gate (register-only) + skip store + z -> LDS (bf16, B-operand layout) ----
    char* zs = lds;    // [128 t][64 r] bf16, 128B rows, same swizzle
    #pragma unroll
    for (int i = 0; i < 2; ++i) {
        int rb = mw * 32 + i * 16 + l4 * 4;
        #pragma unroll
        for (int ni = 0; ni < 4; ++ni) {
            int col = nw * 64 + ni * 16 + l15;
            float z[4];
            #pragma unroll
            for (int j = 0; j < 4; ++j) {
                float a = accA[i][ni][j], g = accG[i][ni][j];
                float th = 1.f - 2.f / (__expf(2.f * a) + 1.f);
                float sg = 1.f / (1.f + __expf(-g));
                z[j] = th * sg;
                skip[(size_t)(b * 64 + rb + j) * T_LEN + t0 + col] = z[j];
            }
            uint p0 = (uint)f2bf(z[0]) | ((uint)f2bf(z[1]) << 16);
            uint p1 = (uint)f2bf(z[2]) | ((uint)f2bf(z[3]) << 16);
            *(uint*)(zs + col * 128 + ((rb * 2) ^ ((col & 7) << 4))) = p0;
            *(uint*)(zs + col * 128 + ((rb * 2 + 4) ^ ((col & 7) << 4))) = p1;
        }
    }
    __syncthreads();

    // ---- phase B: out = Wout @ z + bout ----
    f32x4 accO[2][4];
    #pragma unroll
    for (int i = 0; i < 2; ++i) {
        int rbase = mw * 32 + i * 16 + l4 * 4;
        #pragma unroll
        for (int j = 0; j < 4; ++j) {
            float bo = bout[rbase + j];
            #pragma unroll
            for (int ni = 0; ni < 4; ++ni) accO[i][ni][j] = bo;
        }
    }
    const short8* pA2 = (const short8*)g_packA2;
    #pragma unroll
    for (int s = 0; s < 2; ++s) {
        short8 B[4];
        #pragma unroll
        for (int ni = 0; ni < 4; ++ni) {
            int col = nw * 64 + ni * 16 + l15;
            int bc = s * 64 + l4 * 16;
            B[ni] = *(const short8*)(zs + col * 128 + (bc ^ ((col & 7) << 4)));
        }
        #pragma unroll
        for (int i = 0; i < 2; ++i) {
            short8 Ao = pA2[(s * 4 + mw * 2 + i) * 64 + lane];
            #pragma unroll
            for (int ni = 0; ni < 4; ++ni)
                accO[i][ni] = __builtin_amdgcn_mfma_f32_16x16x32_bf16(Ao, B[ni], accO[i][ni], 0, 0, 0);
        }
    }
    #pragma unroll
    for (int i = 0; i < 2; ++i) {
        int rb = mw * 32 + i * 16 + l4 * 4;
        #pragma unroll
        for (int ni = 0; ni < 4; ++ni) {
            int col = nw * 64 + ni * 16 + l15;
            #pragma unroll
            for (int j = 0; j < 4; ++j)
                out[(size_t)(b * 64 + rb + j) * T_LEN + t0 + col] = accO[i][ni][j];
        }
    }
}

extern "C" void kernel_launch(void* const* d_in, const int* in_sizes, int n_in,
                              void* d_out, int out_size, void* d_ws, size_t ws_size,
                              hipStream_t stream) {
    const float* x     = (const float*)d_in[0];
    const float* cond  = (const float*)d_in[1];
    const float* wconv = (const float*)d_in[2];
    const float* bconv = (const float*)d_in[3];
    const float* wout  = (const float*)d_in[4];
    const float* bout  = (const float*)d_in[5];
    const float* wcond = (const float*)d_in[6];

    float* out  = (float*)d_out;
    float* skip = out + (size_t)8 * 64 * T_LEN;   // outputs concatenated in return order

    pack_weights<<<dim3(160), 256, 0, stream>>>(wconv, wcond, wout);
    wavenet_mfma<<<dim3(8 * (T_LEN / TT)), 256, 0, stream>>>(x, cond, bconv, bout, out, skip);
}

// Round 3
// 86.232 us; speedup vs baseline: 9.8143x; 1.4179x over previous
//
#include <hip/hip_runtime.h>

#define T_LEN 32768
#define TT 128

typedef unsigned short ushort;
typedef unsigned int uint;
typedef __attribute__((ext_vector_type(8))) short short8;   // 8 bf16 (4 VGPRs)
typedef __attribute__((ext_vector_type(4))) float f32x4;

// Fragment-packed bf16 weights (written by pack_weights every launch — deterministic).
__device__ __align__(16) ushort g_packA1[9 * 8 * 64 * 8];   // conv(3 taps)+cond, 9 k-steps x 8 M-frags
__device__ __align__(16) ushort g_packA2[2 * 4 * 64 * 8];   // wout, 2 k-steps x 4 M-frags

static __device__ __forceinline__ ushort f2bf(float f) {    // RNE f32->bf16
    uint u = __float_as_uint(f);
    u += 0x7fffu + ((u >> 16) & 1u);
    return (ushort)(u >> 16);
}

// A-fragment layout for mfma_f32_16x16x32_bf16: lane l holds A[16m + (l&15)][32s + (l>>4)*8 + j]
__global__ void pack_weights(const float* __restrict__ wconv,
                             const float* __restrict__ wcond,
                             const float* __restrict__ wout) {
    int idx = blockIdx.x * 256 + threadIdx.x;
    if (idx < 9 * 8 * 64 * 8) {
        int j = idx & 7, l = (idx >> 3) & 63, m = (idx >> 9) & 7, s = idx >> 12;
        int row = m * 16 + (l & 15);
        int k = s * 32 + ((l >> 4) << 3) + j;          // 0..287
        float v;
        if (k < 192) v = wconv[row * 192 + (k & 63) * 3 + (k >> 6)];   // tap = k/64, c = k%64
        else { int cc = k - 192; v = (cc < 80) ? wcond[row * 80 + cc] : 0.f; }
        g_packA1[idx] = f2bf(v);
    } else {
        int e = idx - 9 * 8 * 64 * 8;                   // 4096 elems
        int j = e & 7, l = (e >> 3) & 63, m = (e >> 9) & 3, s = e >> 11;
        int row = m * 16 + (l & 15);
        int k = s * 32 + ((l >> 4) << 3) + j;           // 0..63
        g_packA2[e] = f2bf(wout[row * 64 + k]);
    }
}

// Staging item: 8 channels (one octet) x 4 t (one quad).
// 8 batched dwordx4 loads (coalesced across lanes: lane->tq), 4 conflict-free ds_write_b128.
static __device__ __forceinline__ void stage_x_item(
    const float* __restrict__ x, char* xs, int b, int t0, int oct, int tq)
{
    int tl = tq * 4;
    int gt0 = t0 - 16 + tl;           // halo=16 = 4 quads -> guard is whole-quad
    f32x4 v[8];
    if (gt0 >= 0) {
        #pragma unroll
        for (int j = 0; j < 8; ++j)
            v[j] = *(const f32x4*)(x + (size_t)(b * 64 + oct * 8 + j) * T_LEN + gt0);
    } else {
        #pragma unroll
        for (int j = 0; j < 8; ++j) v[j] = (f32x4){0.f, 0.f, 0.f, 0.f};
    }
    uint swz = ((uint)tq & 7) << 4;   // == ((t>>2)&7)<<4 for all 4 rows of the quad
    #pragma unroll
    for (int r = 0; r < 4; ++r) {
        short8 p;
        #pragma unroll
        for (int j = 0; j < 8; ++j) p[j] = (short)f2bf(v[j][r]);
        *(short8*)(xs + (tl + r) * 128 + ((uint)(oct * 16) ^ swz)) = p;
    }
}

static __device__ __forceinline__ void stage_c_item(
    const float* __restrict__ cond, char* cs, int b, int t0, int oct, int tq, bool zero)
{
    int tl = tq * 4;
    f32x4 v[8];
    if (!zero) {
        #pragma unroll
        for (int j = 0; j < 8; ++j)
            v[j] = *(const f32x4*)(cond + (size_t)(b * 80 + oct * 8 + j) * T_LEN + t0 + tl);
    } else {
        #pragma unroll
        for (int j = 0; j < 8; ++j) v[j] = (f32x4){0.f, 0.f, 0.f, 0.f};
    }
    uint swz = ((uint)tq & 7) << 4;
    #pragma unroll
    for (int r = 0; r < 4; ++r) {
        short8 p;
        #pragma unroll
        for (int j = 0; j < 8; ++j) p[j] = (short)f2bf(v[j][r]);
        *(short8*)(cs + (tl + r) * 256 + ((uint)(oct * 16) ^ swz)) = p;
    }
}

// 4 waves as 2x2 (mw x nw). Wave computes rows {32mw..+32} U {64+32mw..+32} x cols {64nw..+64}.
// Gate pairs (r, r+64) live in the same lane/reg -> register-only gate.
__global__ __launch_bounds__(256) void wavenet_mfma(
    const float* __restrict__ x, const float* __restrict__ cond,
    const float* __restrict__ bconv, const float* __restrict__ bout,
    float* __restrict__ out, float* __restrict__ skip)
{
    // xs: [144 t][64 c] bf16, 128B rows, XOR swizzle byte^=((t>>2)&7)<<4; zs overlays later.
    // cs: [128 t][128 cc slots] bf16 (only cc<96 used, 80..95 zeroed), 256B rows, same swizzle.
    __shared__ __align__(16) char lds[18432 + 32768];
    char* xs = lds;
    char* cs = lds + 18432;

    const int b   = blockIdx.x >> 8;
    const int t0  = (blockIdx.x & 255) * TT;
    const int tid = threadIdx.x;

    // ---- stage x: items = oct(0..7) x tq(0..35) = 288 ----
    stage_x_item(x, xs, b, t0, tid >> 5, tid & 31);
    if (tid < 32) stage_x_item(x, xs, b, t0, tid >> 2, 32 + (tid & 3));
    // ---- stage cond: items = oct(0..11) x tq(0..31); octets 10,11 are the zero pad ----
    stage_c_item(cond, cs, b, t0, tid >> 5, tid & 31, false);
    if (tid < 128) {
        int oct = 8 + (tid >> 5);
        stage_c_item(cond, cs, b, t0, oct, tid & 31, oct >= 10);
    }
    __syncthreads();

    const int lane = tid & 63;
    const int wv = tid >> 6;
    const int mw = wv & 1, nw = wv >> 1;
    const int l4 = lane >> 4, l15 = lane & 15;

    // ---- phase A: y = Wconv(*)x + Wcond*c + bconv ----
    f32x4 accA[2][4], accG[2][4];
    #pragma unroll
    for (int i = 0; i < 2; ++i) {
        int rbase = mw * 32 + i * 16 + l4 * 4;
        #pragma unroll
        for (int j = 0; j < 4; ++j) {
            float ba = bconv[rbase + j];
            float bg = bconv[64 + rbase + j];
            #pragma unroll
            for (int ni = 0; ni < 4; ++ni) { accA[i][ni][j] = ba; accG[i][ni][j] = bg; }
        }
    }

    const short8* pA1 = (const short8*)g_packA1;
    #pragma unroll
    for (int s = 0; s < 9; ++s) {
        short8 B[4];
        #pragma unroll
        for (int ni = 0; ni < 4; ++ni) {
            int col = nw * 64 + ni * 16 + l15;
            if (s < 6) {   // conv tap s>>1, c-half s&1: B[k=c][n=t], tap shifts t by 8*tap
                int tl = col + (s >> 1) * 8;
                int bc = (s & 1) * 64 + l4 * 16;
                B[ni] = *(const short8*)(xs + tl * 128 + (bc ^ (((tl >> 2) & 7) << 4)));
            } else {       // cond k-step
                int bc = (s - 6) * 64 + l4 * 16;
                B[ni] = *(const short8*)(cs + col * 256 + (bc ^ (((col >> 2) & 7) << 4)));
            }
        }
        #pragma unroll
        for (int i = 0; i < 2; ++i) {
            short8 Aa = pA1[(s * 8 + mw * 2 + i) * 64 + lane];
            short8 Ag = pA1[(s * 8 + 4 + mw * 2 + i) * 64 + lane];
            #pragma unroll
            for (int ni = 0; ni < 4; ++ni) {
                accA[i][ni] = __builtin_amdgcn_mfma_f32_16x16x32_bf16(Aa, B[ni], accA[i][ni], 0, 0, 0);
                accG[i][ni] = __builtin_amdgcn_mfma_f32_16x16x32_bf16(Ag, B[ni], accG[i][ni], 0, 0, 0);
            }
        }
    }
    __syncthreads();   // all xs reads done -> safe to overlay zs

    // ---- gate (register-only) + skip store + z -> LDS (bf16, B-operand layout) ----
    char* zs = lds;    // [128 t][64 r] bf16, 128B rows, same swizzle on col
    #pragma unroll
    for (int i = 0; i < 2; ++i) {
        int rb = mw * 32 + i * 16 + l4 * 4;
        #pragma unroll
        for (int ni = 0; ni < 4; ++ni) {
            int col = nw * 64 + ni * 16 + l15;
            uint cswz = ((uint)(col >> 2) & 7) << 4;
            float z[4];
            #pragma unroll
            for (int j = 0; j < 4; ++j) {
                float a = accA[i][ni][j], g = accG[i][ni][j];
                float th = 1.f - 2.f / (__expf(2.f * a) + 1.f);
                float sg = 1.f / (1.f + __expf(-g));
                z[j] = th * sg;
                skip[(size_t)(b * 64 + rb + j) * T_LEN + t0 + col] = z[j];
            }
            uint p0 = (uint)f2bf(z[0]) | ((uint)f2bf(z[1]) << 16);
            uint p1 = (uint)f2bf(z[2]) | ((uint)f2bf(z[3]) << 16);
            *(uint*)(zs + col * 128 + ((uint)(rb * 2) ^ cswz)) = p0;
            *(uint*)(zs + col * 128 + ((uint)(rb * 2 + 4) ^ cswz)) = p1;
        }
    }
    __syncthreads();

    // ---- phase B: out = Wout @ z + bout ----
    f32x4 accO[2][4];
    #pragma unroll
    for (int i = 0; i < 2; ++i) {
        int rbase = mw * 32 + i * 16 + l4 * 4;
        #pragma unroll
        for (int j = 0; j < 4; ++j) {
            float bo = bout[rbase + j];
            #pragma unroll
            for (int ni = 0; ni < 4; ++ni) accO[i][ni][j] = bo;
        }
    }
    const short8* pA2 = (const short8*)g_packA2;
    #pragma unroll
    for (int s = 0; s < 2; ++s) {
        short8 B[4];
        #pragma unroll
        for (int ni = 0; ni < 4; ++ni) {
            int col = nw * 64 + ni * 16 + l15;
            int bc = s * 64 + l4 * 16;
            B[ni] = *(const short8*)(zs + col * 128 + (bc ^ (((col >> 2) & 7) << 4)));
        }
        #pragma unroll
        for (int i = 0; i < 2; ++i) {
            short8 Ao = pA2[(s * 4 + mw * 2 + i) * 64 + lane];
            #pragma unroll
            for (int ni = 0; ni < 4; ++ni)
                accO[i][ni] = __builtin_amdgcn_mfma_f32_16x16x32_bf16(Ao, B[ni], accO[i][ni], 0, 0, 0);
        }
    }
    #pragma unroll
    for (int i = 0; i < 2; ++i) {
        int rb = mw * 32 + i * 16 + l4 * 4;
        #pragma unroll
        for (int ni = 0; ni < 4; ++ni) {
            int col = nw * 64 + ni * 16 + l15;
            #pragma unroll
            for (int j = 0; j < 4; ++j)
                out[(size_t)(b * 64 + rb + j) * T_LEN + t0 + col] = accO[i][ni][j];
        }
    }
}

extern "C" void kernel_launch(void* const* d_in, const int* in_sizes, int n_in,
                              void* d_out, int out_size, void* d_ws, size_t ws_size,
                              hipStream_t stream) {
    const float* x     = (const float*)d_in[0];
    const float* cond  = (const float*)d_in[1];
    const float* wconv = (const float*)d_in[2];
    const float* bconv = (const float*)d_in[3];
    const float* wout  = (const float*)d_in[4];
    const float* bout  = (const float*)d_in[5];
    const float* wcond = (const float*)d_in[6];

    float* out  = (float*)d_out;
    float* skip = out + (size_t)8 * 64 * T_LEN;   // outputs concatenated in return order

    pack_weights<<<dim3(160), 256, 0, stream>>>(wconv, wcond, wout);
    wavenet_mfma<<<dim3(8 * (T_LEN / TT)), 256, 0, stream>>>(x, cond, bconv, bout, out, skip);
}